// Round 4
// baseline (344.576 us; speedup 1.0000x reference)
//
#include <hip/hip_runtime.h>

// MaxUnpooling2D: out[b, 2h+dh, 2w+dw, c] = updates[b,h,w,c] where mask encodes
// the per-batch flat index ((2h+dh)*WO + (2w+dw))*C + c; all other positions 0.
// Index structure guarantees each input cell scatters only inside its own 2x2
// window -> invert to a gather. R4: OUTPUT-centric — one thread per output
// float4, store address == thread id => one perfectly linear 256 MiB write
// stream (nt). Each input cell is read by the 4 output threads of its window;
// readers sit within a 16-block window so L1/L2 serve the reuse — loads are
// cached (NOT nontemporal). Total HBM traffic: 128 MiB read + 256 MiB write.

constexpr int B  = 16;
constexpr int H  = 128;
constexpr int W  = 128;
constexpr int C  = 64;
constexpr int UP = 2;
constexpr int HO = H * UP;   // 256
constexpr int WO = W * UP;   // 256
constexpr int C4 = C / 4;    // 16 float4 per channel-row

typedef float f32x4 __attribute__((ext_vector_type(4)));
typedef int   i32x4 __attribute__((ext_vector_type(4)));

__global__ __launch_bounds__(256) void unpool_gather(
    const f32x4* __restrict__ upd,   // [B*H*W*C4]
    const i32x4* __restrict__ msk,   // [B*H*W*C4]
    f32x4*       __restrict__ out)   // [B*HO*WO*C4]
{
    const int t = blockIdx.x * blockDim.x + threadIdx.x;   // [0, B*HO*WO*C4)

    // output decode: c4 (4b), col (8b), row (8b), b (4b)
    const int c4  = t & (C4 - 1);
    const int col = (t >> 4) & (WO - 1);
    const int row = (t >> 12) & (HO - 1);
    const int b   = t >> 20;

    // source pooled cell
    const int h = row >> 1;
    const int w = col >> 1;
    const int iidx = ((b * H + h) * W + w) * C4 + c4;

    const f32x4 u = upd[iidx];   // cached: 4-way reuse across window threads
    const i32x4 m = msk[iidx];

    // per-batch flat float index of component 0 at this output position
    const int flat0 = (row * WO + col) * C + c4 * 4;

    f32x4 v;
    v.x = (m.x == flat0 + 0) ? u.x : 0.0f;
    v.y = (m.y == flat0 + 1) ? u.y : 0.0f;
    v.z = (m.z == flat0 + 2) ? u.z : 0.0f;
    v.w = (m.w == flat0 + 3) ? u.w : 0.0f;

    __builtin_nontemporal_store(v, &out[t]);   // dense linear write stream
}

extern "C" void kernel_launch(void* const* d_in, const int* in_sizes, int n_in,
                              void* d_out, int out_size, void* d_ws, size_t ws_size,
                              hipStream_t stream) {
    const f32x4* upd = (const f32x4*)d_in[0];
    const i32x4* msk = (const i32x4*)d_in[1];
    f32x4*       out = (f32x4*)d_out;

    const int n_threads = B * HO * WO * C4;        // 16,777,216
    const int block = 256;
    const int grid  = n_threads / block;           // 65,536

    unpool_gather<<<grid, block, 0, stream>>>(upd, msk, out);
}